// Round 4
// baseline (561.849 us; speedup 1.0000x reference)
//
#include <hip/hip_runtime.h>
#include <hip/hip_bf16.h>
#include <stdint.h>

typedef __bf16 bf16x8 __attribute__((ext_vector_type(8)));
typedef float f32x4 __attribute__((ext_vector_type(4)));
typedef unsigned short ushort8v __attribute__((ext_vector_type(8)));

// Problem constants
#define NB    16
#define CIN   256
#define COUT  256
#define HH    128
#define WW    128

// ws layout (bytes)
#define OFF_ZROW  0u                    // 65536 zeroed page (one fake xT row)
#define OFF_COFF  (1u << 16)            // 2*16*256 f32 = 8 KB
#define OFF_TMPS  (1u << 17)            // 16*16*768 f32 = 768 KB
#define OFF_WEFF  (1u << 20)            // 16*9*256*256 bf16 = 18 MB
#define OFF_XT    (20u * 1024u * 1024u) // G * 8 MB bf16 channels-last x
#define XT_PER_B  (128u * 128u * 256u * 2u)

#define WAITVM(N) asm volatile("s_waitcnt vmcnt(" #N ")" ::: "memory")

__device__ inline void gload16(const void* g, void* l) {
  __builtin_amdgcn_global_load_lds(
      (const __attribute__((address_space(1))) void*)g,
      (__attribute__((address_space(3))) void*)l, 16, 0, 0);
}

__device__ inline ushort f2bf(float f) {
  __hip_bfloat16 h = __float2bfloat16(f);
  union { __hip_bfloat16 b; ushort u; } cv;
  cv.b = h;
  return cv.u;
}

// ---------------- kernel 1: embed MLP -> coff[2][16][16][16] ----------------
__global__ void k_coff(const float* __restrict__ wms,
                       const float* __restrict__ w1a, const float* __restrict__ b1a,
                       const float* __restrict__ w2a, const float* __restrict__ b2a,
                       const float* __restrict__ w1b, const float* __restrict__ b1b,
                       const float* __restrict__ w2b, const float* __restrict__ b2b,
                       float* __restrict__ coff) {
  int br = blockIdx.x >> 4, b = blockIdx.x & 15;
  const float* w1 = br ? w1b : w1a;
  const float* b1 = br ? b1b : b1a;
  const float* w2 = br ? w2b : w2a;
  const float* b2 = br ? b2b : b2a;
  const float* v = wms + (br * 16 + b) * 32;
  __shared__ float h[128];
  int t = threadIdx.x;
  if (t < 128) {
    float a = b1[t];
#pragma unroll
    for (int i = 0; i < 32; ++i) a += w1[t * 32 + i] * v[i];
    h[t] = a >= 0.f ? a : 0.2f * a;
  }
  __syncthreads();
  float a = b2[t];
  for (int j = 0; j < 128; ++j) a += w2[t * 128 + j] * h[j];
  coff[(br * 16 + b) * 256 + t] = a;
}

// ------------- kernel 2a: tmpS[b][r][c] = coff1@A1 + coff2@A2 ---------------
__global__ void k_tmps(const float* __restrict__ coff,
                       const float* __restrict__ A1, const float* __restrict__ A2,
                       float* __restrict__ tmpS) {
  int b = blockIdx.x >> 4, r = blockIdx.x & 15;
  __shared__ float c1[16], c2[16];
  int t = threadIdx.x;
  if (t < 16) {
    c1[t] = coff[b * 256 + r * 16 + t];
    c2[t] = coff[(16 + b) * 256 + r * 16 + t];
  }
  __syncthreads();
  for (int c = t; c < 768; c += 256) {
    float s = 0.f;
#pragma unroll
    for (int q = 0; q < 16; ++q) s += c1[q] * A1[q * 768 + c] + c2[q] * A2[q * 768 + c];
    tmpS[(b * 16 + r) * 768 + c] = s;
  }
}

// ------- kernel 2b: Weff[b][tt][co][ci] = conv_w + loraB @ tmpS (bf16) -------
__global__ __launch_bounds__(256) void k_weff(const float* __restrict__ conv_w,
                                              const float* __restrict__ loraB,
                                              const float* __restrict__ tmpS,
                                              __hip_bfloat16* __restrict__ Weff) {
  int bid = blockIdx.x;
  int co = bid & 255, b = bid >> 8;
  int t = threadIdx.x;
  __shared__ float Bs[3][16];
  __shared__ ushort obuf[2304];
  if (t < 48) Bs[t >> 4][t & 15] = loraB[(co * 3 + (t >> 4)) * 16 + (t & 15)];
  __syncthreads();
  const float* T = tmpS + (size_t)b * 16 * 768;
  const float* W = conv_w + (size_t)co * 2304;
#pragma unroll
  for (int k = 0; k < 3; ++k) {
#pragma unroll
    for (int cc = 0; cc < 3; ++cc) {
      int c = cc * 256 + t;
      float s = W[k * 768 + c];
#pragma unroll
      for (int r = 0; r < 16; ++r) s += Bs[k][r] * T[r * 768 + c];
      int f = k * 768 + c;  // local flat over (ci,kh,kw) for this co
      int ci = f / 9, tt = f - ci * 9;
      obuf[tt * 256 + ci] = f2bf(s);
    }
  }
  __syncthreads();
#pragma unroll
  for (int tt = 0; tt < 9; ++tt)
    ((ushort*)Weff)[((size_t)(b * 9 + tt) * 256 + co) * 256 + t] = obuf[tt * 256 + t];
}

// -------- kernel 3: x (f32, NCHW) -> xT (bf16, N H W C channels-last) --------
__global__ __launch_bounds__(256) void k_xt(const float* __restrict__ x,
                                            __hip_bfloat16* __restrict__ xT, int b0) {
  __shared__ ushort t[32][132];
  int bid = blockIdx.x;
  int cb = bid & 7, h = (bid >> 3) & 127, bp = bid >> 10;
  int b = b0 + bp;
  int tid = threadIdx.x;
  int ci2 = tid >> 5, w4 = (tid & 31) * 4;
  const float* srcb = x + ((size_t)(b * 256 + cb * 32) * 128 + h) * 128;
#pragma unroll
  for (int k = 0; k < 4; ++k) {
    int c = ci2 + k * 8;
    float4 v = *(const float4*)(srcb + (size_t)c * 16384 + w4);
    ushort4 u;
    u.x = f2bf(v.x);
    u.y = f2bf(v.y);
    u.z = f2bf(v.z);
    u.w = f2bf(v.w);
    *(ushort4*)&t[c][w4] = u;
  }
  __syncthreads();
  int w = tid >> 1, hf = tid & 1;
  ushort8v o0, o1;
#pragma unroll
  for (int j = 0; j < 8; ++j) {
    o0[j] = t[hf * 16 + j][w];
    o1[j] = t[hf * 16 + 8 + j][w];
  }
  ushort* dst = (ushort*)xT + (size_t)bp * 128 * 128 * 256 +
                ((size_t)h * 128 + w) * 256 + cb * 32 + hf * 16;
  *(ushort8v*)dst = o0;
  *(ushort8v*)(dst + 8) = o1;
}

// ------------------- kernel 4: per-sample implicit-GEMM conv ------------------
// Counted-vmcnt pipeline (T3+T4): 72 steps of one (cb8,kh,kw) tap.
// W-slab (16KB) TRIPLE-buffered, staged 2 steps ahead; x-tile (33KB) double-
// buffered, staged 9 steps ahead. Raw s_barrier + s_waitcnt vmcnt(N) per step
// (N=6 taps 0-1, N=2 taps 2-8) -- loads stay in flight across barriers.
// MFMA 16x16x32 bf16; frag patterns = round-2 (measured 0 bank conflicts).
// LDS granule swizzle g' = g ^ ((row>>1)&3) source-side + read-side.
__global__ __launch_bounds__(512) void k_conv(
    const __hip_bfloat16* __restrict__ xT,
    const __hip_bfloat16* __restrict__ Weff,
    const __hip_bfloat16* __restrict__ zrow,
    const float* __restrict__ cbias,
    float* __restrict__ out, int b0) {
  // xs[buf][ri][wi][ci]: 2 x 4 x 130 x 32 (wi 0 and 129 are zero pads)
  __shared__ __align__(16) __hip_bfloat16 xs[2 * 4 * 130 * 32];  // 66,560 B
  // wsl[slot][co][ci]: 3 x 256 x 32, one (kh,kw) tap slab per slot
  __shared__ __align__(16) __hip_bfloat16 wsl[3 * 256 * 32];     // 49,152 B

  int bid = blockIdx.x;
  int hp = bid & 63, bp = bid >> 6;
  int b = b0 + bp;
  int h0 = hp * 2;

  int tid = threadIdx.x;
  int wid = tid >> 6, lane = tid & 63;
  int l15 = lane & 15, lh = lane >> 4;
  int wm = wid >> 2, wn = wid & 3;
  int row = wn >> 1, w0 = (wn & 1) * 64;
  int lrow = lane >> 2;
  int sgx = (lane & 3) ^ (((1 + lrow) >> 1) & 3);  // x-stage source granule
  int sgw = (lane & 3) ^ ((lrow >> 1) & 3);        // w-stage source granule
  int asw = (l15 >> 1) & 3;                        // A-frag read swizzle

  // zero the w-pad columns of BOTH x buffers (512 entries, one per thread)
  ((ushort*)xs)[(tid >> 8) * 16640 + ((tid >> 6) & 3) * 4160 +
                (((tid >> 5) & 1) ? 129 * 32 : 0) + (tid & 31)] = 0;

  const __hip_bfloat16* xTb = xT + (size_t)bp * 128 * 128 * 256;

  // ---- prologue: issue x(group 0), W(step 0), W(step 1); drain once ----
  {
#pragma unroll
    for (int k = 0; k < 4; ++k) {
      int s = wid * 4 + k;
      int ri = s >> 3, wblk = s & 7;
      int h = h0 + ri - 1;
      const __hip_bfloat16* srow = (h >= 0 && h < 128) ? (xTb + (size_t)h * 128 * 256) : zrow;
      gload16(srow + (wblk * 16 + lrow) * 256 + sgx * 8,
              xs + ri * 4160 + (1 + wblk * 16) * 32);
    }
    int cblk = wid * 2;
#pragma unroll
    for (int st = 0; st < 2; ++st)
#pragma unroll
      for (int k = 0; k < 2; ++k)
        gload16(Weff + (((size_t)(b * 9 + st) * 256 + (cblk + k) * 16 + lrow) * 256 + sgw * 8),
                wsl + st * 8192 + (cblk + k) * 512);
  }

  f32x4 acc[8][4];
#pragma unroll
  for (int mf = 0; mf < 8; ++mf)
#pragma unroll
    for (int nf = 0; nf < 4; ++nf) acc[mf][nf] = (f32x4){0.f, 0.f, 0.f, 0.f};

  // x + W0 must be ready; W1 (newest 2 loads) may stay in flight. Pads need lgkm.
  asm volatile("s_waitcnt vmcnt(2) lgkmcnt(0)" ::: "memory");
  __builtin_amdgcn_s_barrier();

#pragma unroll 1
  for (int g = 0; g < 8; ++g) {
    const __hip_bfloat16* xsb = xs + (g & 1) * 16640;
#pragma unroll
    for (int kh = 0; kh < 3; ++kh) {
#pragma unroll
      for (int kw = 0; kw < 3; ++kw) {
        const int t = kh * 3 + kw;            // compile-time tap
        const int slot = t % 3;               // = (9g+t) % 3, compile-time
        const __hip_bfloat16* wcur = wsl + slot * 8192;

        // ---- issue W(i+2) into slot (t+2)%3 ----
        if (g < 7 || t < 7) {
          const int tap2 = (t + 2) % 9;       // compile-time
          int g2 = g + (t + 2) / 9;           // runtime
          int cblk = wid * 2;
#pragma unroll
          for (int k = 0; k < 2; ++k)
            gload16(Weff + (((size_t)(b * 9 + tap2) * 256 + (cblk + k) * 16 + lrow) * 256 +
                            g2 * 32 + sgw * 8),
                    wsl + ((t + 2) % 3) * 8192 + (cblk + k) * 512);
        }
        // ---- issue x(group g+1) (9 steps of lead) ----
        if (t == 0 && g < 7) {
          __hip_bfloat16* xnxt = xs + ((g + 1) & 1) * 16640;
          int c0n = (g + 1) * 32;
#pragma unroll
          for (int k = 0; k < 4; ++k) {
            int s = wid * 4 + k;
            int ri = s >> 3, wblk = s & 7;
            int h = h0 + ri - 1;
            const __hip_bfloat16* srow = (h >= 0 && h < 128) ? (xTb + (size_t)h * 128 * 256) : zrow;
            gload16(srow + (wblk * 16 + lrow) * 256 + c0n + sgx * 8,
                    xnxt + ri * 4160 + (1 + wblk * 16) * 32);
          }
        }

        // ---- frags from LDS (round-2 patterns, 0-conflict) ----
        int bsw = ((l15 + kw) >> 1) & 3;
        bf16x8 af[8], bfr[4];
#pragma unroll
        for (int mf = 0; mf < 8; ++mf)
          af[mf] = *(const bf16x8*)&wcur[(wm * 128 + mf * 16 + l15) * 32 + ((lh ^ asw) * 8)];
#pragma unroll
        for (int nf = 0; nf < 4; ++nf)
          bfr[nf] = *(const bf16x8*)&xsb[(row + kh) * 4160 +
                                         (w0 + nf * 16 + l15 + kw) * 32 + ((lh ^ bsw) * 8)];

        __builtin_amdgcn_s_setprio(1);
#pragma unroll
        for (int mf = 0; mf < 8; ++mf)
#pragma unroll
          for (int nf = 0; nf < 4; ++nf)
            acc[mf][nf] = __builtin_amdgcn_mfma_f32_16x16x32_bf16(af[mf], bfr[nf],
                                                                  acc[mf][nf], 0, 0, 0);
        __builtin_amdgcn_s_setprio(0);

        // ---- counted-vmcnt barrier (never a full drain in steady state) ----
        if (g == 7) {
          if (t < 7) {
            WAITVM(2);
            __builtin_amdgcn_s_barrier();
          } else if (t == 7) {
            WAITVM(0);
            __builtin_amdgcn_s_barrier();
          }
          // t == 8: last step, no barrier
        } else {
          if (t < 2) {
            WAITVM(6);  // allow W(i+2) + x(next group) in flight
            __builtin_amdgcn_s_barrier();
          } else {
            WAITVM(2);  // allow W(i+2) in flight
            __builtin_amdgcn_s_barrier();
          }
        }
      }
    }
  }

  // epilogue: D[m][n]: m(co) = (lane>>4)*4 + r, n(px) = lane&15
#pragma unroll
  for (int mf = 0; mf < 8; ++mf) {
    int cobase = wm * 128 + mf * 16 + lh * 4;
#pragma unroll
    for (int r = 0; r < 4; ++r) {
      int co = cobase + r;
      float bias = cbias[co];
      size_t obase = ((size_t)(b * 256 + co) * 128 + (h0 + row)) * 128 + w0 + l15;
#pragma unroll
      for (int nf = 0; nf < 4; ++nf) out[obase + nf * 16] = acc[mf][nf][r] + bias;
    }
  }
}

extern "C" void kernel_launch(void* const* d_in, const int* in_sizes, int n_in,
                              void* d_out, int out_size, void* d_ws, size_t ws_size,
                              hipStream_t stream) {
  const float* x      = (const float*)d_in[0];
  const float* wms    = (const float*)d_in[1];
  const float* conv_w = (const float*)d_in[2];
  const float* conv_b = (const float*)d_in[3];
  const float* e1w1   = (const float*)d_in[4];
  const float* e1b1   = (const float*)d_in[5];
  const float* e1w2   = (const float*)d_in[6];
  const float* e1b2   = (const float*)d_in[7];
  const float* e2w1   = (const float*)d_in[8];
  const float* e2b1   = (const float*)d_in[9];
  const float* e2w2   = (const float*)d_in[10];
  const float* e2b2   = (const float*)d_in[11];
  const float* A1     = (const float*)d_in[12];
  const float* A2     = (const float*)d_in[13];
  const float* loraB  = (const float*)d_in[14];
  float* out = (float*)d_out;

  uint8_t* ws = (uint8_t*)d_ws;
  __hip_bfloat16* zrow = (__hip_bfloat16*)(ws + OFF_ZROW);
  float* coff          = (float*)(ws + OFF_COFF);
  float* tmpS          = (float*)(ws + OFF_TMPS);
  __hip_bfloat16* Weff = (__hip_bfloat16*)(ws + OFF_WEFF);
  __hip_bfloat16* xT   = (__hip_bfloat16*)(ws + OFF_XT);

  // group size: how many samples' xT fit in ws
  int G = 16;
  while (G > 1 && (size_t)OFF_XT + (size_t)G * XT_PER_B > ws_size) G >>= 1;

  hipMemsetAsync(zrow, 0, 65536, stream);
  k_coff<<<32, 256, 0, stream>>>(wms, e1w1, e1b1, e1w2, e1b2, e2w1, e2b1, e2w2, e2b2, coff);
  k_tmps<<<256, 256, 0, stream>>>(coff, A1, A2, tmpS);
  k_weff<<<16 * 256, 256, 0, stream>>>(conv_w, loraB, tmpS, Weff);
  for (int g = 0; g < 16; g += G) {
    k_xt<<<G * 1024, 256, 0, stream>>>(x, xT, g);
    k_conv<<<G * 64, 512, 0, stream>>>(xT, Weff, zrow, conv_b, out, g);
  }
}

// Round 5
// 553.795 us; speedup vs baseline: 1.0145x; 1.0145x over previous
//
#include <hip/hip_runtime.h>
#include <hip/hip_bf16.h>
#include <stdint.h>

typedef __bf16 bf16x8 __attribute__((ext_vector_type(8)));
typedef float f32x4 __attribute__((ext_vector_type(4)));
typedef unsigned short ushort8v __attribute__((ext_vector_type(8)));

// Problem constants
#define NB    16
#define CIN   256
#define COUT  256
#define HH    128
#define WW    128

// ws layout (bytes)
#define OFF_ZROW  0u                    // 65536 zeroed page (one fake xT row)
#define OFF_COFF  (1u << 16)            // 2*16*256 f32 = 8 KB
#define OFF_TMPS  (1u << 17)            // 16*16*768 f32 = 768 KB
#define OFF_WEFF  (1u << 20)            // 16*9*256*256 bf16 = 18 MB
#define OFF_XT    (20u * 1024u * 1024u) // G * 8 MB bf16 channels-last x
#define XT_PER_B  (128u * 128u * 256u * 2u)

#define WAITVM0() asm volatile("s_waitcnt vmcnt(0)" ::: "memory")

__device__ inline void gload16(const void* g, void* l) {
  __builtin_amdgcn_global_load_lds(
      (const __attribute__((address_space(1))) void*)g,
      (__attribute__((address_space(3))) void*)l, 16, 0, 0);
}

__device__ inline ushort f2bf(float f) {
  __hip_bfloat16 h = __float2bfloat16(f);
  union { __hip_bfloat16 b; ushort u; } cv;
  cv.b = h;
  return cv.u;
}

// ---------------- kernel 1: embed MLP -> coff[2][16][16][16] ----------------
__global__ void k_coff(const float* __restrict__ wms,
                       const float* __restrict__ w1a, const float* __restrict__ b1a,
                       const float* __restrict__ w2a, const float* __restrict__ b2a,
                       const float* __restrict__ w1b, const float* __restrict__ b1b,
                       const float* __restrict__ w2b, const float* __restrict__ b2b,
                       float* __restrict__ coff) {
  int br = blockIdx.x >> 4, b = blockIdx.x & 15;
  const float* w1 = br ? w1b : w1a;
  const float* b1 = br ? b1b : b1a;
  const float* w2 = br ? w2b : w2a;
  const float* b2 = br ? b2b : b2a;
  const float* v = wms + (br * 16 + b) * 32;
  __shared__ float h[128];
  int t = threadIdx.x;
  if (t < 128) {
    float a = b1[t];
#pragma unroll
    for (int i = 0; i < 32; ++i) a += w1[t * 32 + i] * v[i];
    h[t] = a >= 0.f ? a : 0.2f * a;
  }
  __syncthreads();
  float a = b2[t];
  for (int j = 0; j < 128; ++j) a += w2[t * 128 + j] * h[j];
  coff[(br * 16 + b) * 256 + t] = a;
}

// ------------- kernel 2a: tmpS[b][r][c] = coff1@A1 + coff2@A2 ---------------
__global__ void k_tmps(const float* __restrict__ coff,
                       const float* __restrict__ A1, const float* __restrict__ A2,
                       float* __restrict__ tmpS) {
  int b = blockIdx.x >> 4, r = blockIdx.x & 15;
  __shared__ float c1[16], c2[16];
  int t = threadIdx.x;
  if (t < 16) {
    c1[t] = coff[b * 256 + r * 16 + t];
    c2[t] = coff[(16 + b) * 256 + r * 16 + t];
  }
  __syncthreads();
  for (int c = t; c < 768; c += 256) {
    float s = 0.f;
#pragma unroll
    for (int q = 0; q < 16; ++q) s += c1[q] * A1[q * 768 + c] + c2[q] * A2[q * 768 + c];
    tmpS[(b * 16 + r) * 768 + c] = s;
  }
}

// ------- kernel 2b: Weff[b][tt][co][ci] = conv_w + loraB @ tmpS (bf16) -------
__global__ __launch_bounds__(256) void k_weff(const float* __restrict__ conv_w,
                                              const float* __restrict__ loraB,
                                              const float* __restrict__ tmpS,
                                              __hip_bfloat16* __restrict__ Weff) {
  int bid = blockIdx.x;
  int co = bid & 255, b = bid >> 8;
  int t = threadIdx.x;
  __shared__ float Bs[3][16];
  __shared__ ushort obuf[2304];
  if (t < 48) Bs[t >> 4][t & 15] = loraB[(co * 3 + (t >> 4)) * 16 + (t & 15)];
  __syncthreads();
  const float* T = tmpS + (size_t)b * 16 * 768;
  const float* W = conv_w + (size_t)co * 2304;
#pragma unroll
  for (int k = 0; k < 3; ++k) {
#pragma unroll
    for (int cc = 0; cc < 3; ++cc) {
      int c = cc * 256 + t;
      float s = W[k * 768 + c];
#pragma unroll
      for (int r = 0; r < 16; ++r) s += Bs[k][r] * T[r * 768 + c];
      int f = k * 768 + c;  // local flat over (ci,kh,kw) for this co
      int ci = f / 9, tt = f - ci * 9;
      obuf[tt * 256 + ci] = f2bf(s);
    }
  }
  __syncthreads();
#pragma unroll
  for (int tt = 0; tt < 9; ++tt)
    ((ushort*)Weff)[((size_t)(b * 9 + tt) * 256 + co) * 256 + t] = obuf[tt * 256 + t];
}

// -------- kernel 3: x (f32, NCHW) -> xT (bf16, N H W C channels-last) --------
__global__ __launch_bounds__(256) void k_xt(const float* __restrict__ x,
                                            __hip_bfloat16* __restrict__ xT, int b0) {
  __shared__ ushort t[32][132];
  int bid = blockIdx.x;
  int cb = bid & 7, h = (bid >> 3) & 127, bp = bid >> 10;
  int b = b0 + bp;
  int tid = threadIdx.x;
  int ci2 = tid >> 5, w4 = (tid & 31) * 4;
  const float* srcb = x + ((size_t)(b * 256 + cb * 32) * 128 + h) * 128;
#pragma unroll
  for (int k = 0; k < 4; ++k) {
    int c = ci2 + k * 8;
    float4 v = *(const float4*)(srcb + (size_t)c * 16384 + w4);
    ushort4 u;
    u.x = f2bf(v.x);
    u.y = f2bf(v.y);
    u.z = f2bf(v.z);
    u.w = f2bf(v.w);
    *(ushort4*)&t[c][w4] = u;
  }
  __syncthreads();
  int w = tid >> 1, hf = tid & 1;
  ushort8v o0, o1;
#pragma unroll
  for (int j = 0; j < 8; ++j) {
    o0[j] = t[hf * 16 + j][w];
    o1[j] = t[hf * 16 + 8 + j][w];
  }
  ushort* dst = (ushort*)xT + (size_t)bp * 128 * 128 * 256 +
                ((size_t)h * 128 + w) * 256 + cb * 32 + hf * 16;
  *(ushort8v*)dst = o0;
  *(ushort8v*)(dst + 8) = o1;
}

// ------------------- kernel 4: per-sample implicit-GEMM conv ------------------
// 24 kh-phases per block. Per phase: issue W(p+1) stage (dbuf kh-slab, 48KB),
// then ONE barrier-free region with 3 kw clusters (36 ds_read + 96 MFMA/wave)
// so the compiler overlaps kw+1 frag reads under kw MFMAs; phase ends with
// WAITVM(0)+barrier (stage issued a full phase earlier -> drain ~free).
// x single-buffered, restaged at group boundary behind its own barrier pair.
// Frag patterns + LDS granule swizzle identical to round 2 (0 conflicts).
__global__ __launch_bounds__(512) void k_conv(
    const __hip_bfloat16* __restrict__ xT,
    const __hip_bfloat16* __restrict__ Weff,
    const __hip_bfloat16* __restrict__ zrow,
    const float* __restrict__ cbias,
    float* __restrict__ out, int b0) {
  // xs[ri][wi][ci] : ri 0..3 -> x row h0+ri-1 ; wi 0..129 -> w = wi-1 ; 32 ci
  __shared__ __align__(16) __hip_bfloat16 xs[4 * 130 * 32];       // 33,280 B
  // wbuf[buf][kw][co][ci] : 2 x 3 x 256 x 32 (one kh-slab per buffer)
  __shared__ __align__(16) __hip_bfloat16 wbuf[2 * 3 * 256 * 32]; // 98,304 B

  // XCD-aware swizzle (nwg % 8 == 0 for all G in {1..16})
  int nwg = gridDim.x;
  int bid0 = blockIdx.x;
  int bid = (bid0 & 7) * (nwg >> 3) + (bid0 >> 3);

  int hp = bid & 63, bp = bid >> 6;
  int b = b0 + bp;
  int h0 = hp * 2;

  int tid = threadIdx.x;
  int wid = tid >> 6, lane = tid & 63;
  int l15 = lane & 15, lh = lane >> 4;
  int wm = wid >> 2, wn = wid & 3;
  int row = wn >> 1, w0 = (wn & 1) * 64;
  int lrow = lane >> 2;
  int sgx = (lane & 3) ^ (((1 + lrow) >> 1) & 3);  // x-stage source granule
  int sgw = (lane & 3) ^ ((lrow >> 1) & 3);        // w-stage source granule
  int asw = (l15 >> 1) & 3;                        // A-frag read swizzle

  // zero the w-pad columns (wi = 0 and wi = 129); never overwritten after
  if (tid < 256) {
    int ri = tid >> 6, which = (tid >> 5) & 1, ci = tid & 31;
    ((ushort*)xs)[ri * 4160 + (which ? 129 : 0) * 32 + ci] = 0;
  }

  const __hip_bfloat16* xTb = xT + (size_t)bp * 128 * 128 * 256;

  // ---- prologue: issue x(group 0) + W(phase 0) into wbuf[0]; drain once ----
  {
#pragma unroll
    for (int k = 0; k < 4; ++k) {
      int s = wid * 4 + k;
      int ri = s >> 3, wblk = s & 7;
      int h = h0 + ri - 1;
      const __hip_bfloat16* srow = (h >= 0 && h < 128) ? (xTb + (size_t)h * 128 * 256) : zrow;
      gload16(srow + (wblk * 16 + lrow) * 256 + sgx * 8,
              xs + ri * 4160 + (1 + wblk * 16) * 32);
    }
#pragma unroll
    for (int k = 0; k < 6; ++k) {
      int s = wid * 6 + k;
      int kw = s >> 4, cblk = s & 15;
      gload16(Weff + (((size_t)(b * 9 + kw) * 256 + cblk * 16 + lrow) * 256 + sgw * 8),
              wbuf + kw * 8192 + cblk * 512);
    }
  }

  f32x4 acc[8][4];
#pragma unroll
  for (int mf = 0; mf < 8; ++mf)
#pragma unroll
    for (int nf = 0; nf < 4; ++nf) acc[mf][nf] = (f32x4){0.f, 0.f, 0.f, 0.f};

  __syncthreads();  // prologue staged + pads zeroed

#pragma unroll 1
  for (int g = 0; g < 8; ++g) {
    int c0 = g * 32;
#pragma unroll
    for (int kh = 0; kh < 3; ++kh) {
      const int p = g * 3 + kh;               // kh compile-time; g runtime
      const __hip_bfloat16* wcur = wbuf + (p & 1) * 24576;
      __hip_bfloat16* wnxt = wbuf + ((p + 1) & 1) * 24576;

      // ---- issue W(p+1) stage (6 gload16/wave) ----
      if (g < 7 || kh < 2) {
        const int khn = (kh + 1) % 3;          // compile-time
        int tapbase = b * 9 + khn * 3;
        int c0n = (kh < 2) ? c0 : c0 + 32;
#pragma unroll
        for (int k = 0; k < 6; ++k) {
          int s = wid * 6 + k;
          int kw = s >> 4, cblk = s & 15;
          gload16(Weff + (((size_t)(tapbase + kw) * 256 + cblk * 16 + lrow) * 256 +
                          c0n + sgw * 8),
                  wnxt + kw * 8192 + cblk * 512);
        }
      }

      // ---- barrier-free compute region: 3 kw clusters ----
#pragma unroll
      for (int kw = 0; kw < 3; ++kw) {
        int bsw = ((l15 + kw) >> 1) & 3;
        bf16x8 af[8], bfr[4];
#pragma unroll
        for (int mf = 0; mf < 8; ++mf)
          af[mf] = *(const bf16x8*)&wcur[kw * 8192 + (wm * 128 + mf * 16 + l15) * 32 +
                                         ((lh ^ asw) * 8)];
#pragma unroll
        for (int nf = 0; nf < 4; ++nf)
          bfr[nf] = *(const bf16x8*)&xs[(row + kh) * 4160 +
                                        (w0 + nf * 16 + l15 + kw) * 32 + ((lh ^ bsw) * 8)];
        __builtin_amdgcn_s_setprio(1);
#pragma unroll
        for (int mf = 0; mf < 8; ++mf)
#pragma unroll
          for (int nf = 0; nf < 4; ++nf)
            acc[mf][nf] = __builtin_amdgcn_mfma_f32_16x16x32_bf16(af[mf], bfr[nf],
                                                                  acc[mf][nf], 0, 0, 0);
        __builtin_amdgcn_s_setprio(0);
      }

      // ---- phase end ----
      if (kh < 2) {
        WAITVM0();                     // W(p+1) issued a full phase ago -> ~free
        __builtin_amdgcn_s_barrier();
      } else if (g < 7) {
        WAITVM0();
        __builtin_amdgcn_s_barrier();  // all reads of xs done; W(p+1) arrived
        // restage x for group g+1 (overwrites xs; safe after barrier)
        int c0n = (g + 1) * 32;
#pragma unroll
        for (int k = 0; k < 4; ++k) {
          int s = wid * 4 + k;
          int ri = s >> 3, wblk = s & 7;
          int h = h0 + ri - 1;
          const __hip_bfloat16* srow = (h >= 0 && h < 128) ? (xTb + (size_t)h * 128 * 256) : zrow;
          gload16(srow + (wblk * 16 + lrow) * 256 + c0n + sgx * 8,
                  xs + ri * 4160 + (1 + wblk * 16) * 32);
        }
        WAITVM0();                     // exposed x delivery (~1 us/group total)
        __builtin_amdgcn_s_barrier();
      }
      // last phase (g==7, kh==2): fall through to epilogue
    }
  }

  // epilogue: D[m][n]: m(co) = (lane>>4)*4 + r, n(px) = lane&15
#pragma unroll
  for (int mf = 0; mf < 8; ++mf) {
    int cobase = wm * 128 + mf * 16 + lh * 4;
#pragma unroll
    for (int r = 0; r < 4; ++r) {
      int co = cobase + r;
      float bias = cbias[co];
      size_t obase = ((size_t)(b * 256 + co) * 128 + (h0 + row)) * 128 + w0 + l15;
#pragma unroll
      for (int nf = 0; nf < 4; ++nf) out[obase + nf * 16] = acc[mf][nf][r] + bias;
    }
  }
}

extern "C" void kernel_launch(void* const* d_in, const int* in_sizes, int n_in,
                              void* d_out, int out_size, void* d_ws, size_t ws_size,
                              hipStream_t stream) {
  const float* x      = (const float*)d_in[0];
  const float* wms    = (const float*)d_in[1];
  const float* conv_w = (const float*)d_in[2];
  const float* conv_b = (const float*)d_in[3];
  const float* e1w1   = (const float*)d_in[4];
  const float* e1b1   = (const float*)d_in[5];
  const float* e1w2   = (const float*)d_in[6];
  const float* e1b2   = (const float*)d_in[7];
  const float* e2w1   = (const float*)d_in[8];
  const float* e2b1   = (const float*)d_in[9];
  const float* e2w2   = (const float*)d_in[10];
  const float* e2b2   = (const float*)d_in[11];
  const float* A1     = (const float*)d_in[12];
  const float* A2     = (const float*)d_in[13];
  const float* loraB  = (const float*)d_in[14];
  float* out = (float*)d_out;

  uint8_t* ws = (uint8_t*)d_ws;
  __hip_bfloat16* zrow = (__hip_bfloat16*)(ws + OFF_ZROW);
  float* coff          = (float*)(ws + OFF_COFF);
  float* tmpS          = (float*)(ws + OFF_TMPS);
  __hip_bfloat16* Weff = (__hip_bfloat16*)(ws + OFF_WEFF);
  __hip_bfloat16* xT   = (__hip_bfloat16*)(ws + OFF_XT);

  // group size: how many samples' xT fit in ws
  int G = 16;
  while (G > 1 && (size_t)OFF_XT + (size_t)G * XT_PER_B > ws_size) G >>= 1;

  hipMemsetAsync(zrow, 0, 65536, stream);
  k_coff<<<32, 256, 0, stream>>>(wms, e1w1, e1b1, e1w2, e1b2, e2w1, e2b1, e2w2, e2b2, coff);
  k_tmps<<<256, 256, 0, stream>>>(coff, A1, A2, tmpS);
  k_weff<<<16 * 256, 256, 0, stream>>>(conv_w, loraB, tmpS, Weff);
  for (int g = 0; g < 16; g += G) {
    k_xt<<<G * 1024, 256, 0, stream>>>(x, xT, g);
    k_conv<<<G * 64, 512, 0, stream>>>(xT, Weff, zrow, conv_b, out, g);
  }
}